// Round 1
// 1709.991 us; speedup vs baseline: 1.0515x; 1.0515x over previous
//
#include <hip/hip_runtime.h>
#include <cstdint>
#include <cstddef>

typedef __bf16 bf16;
typedef __bf16 bf16x8 __attribute__((ext_vector_type(8)));
typedef float f32x4 __attribute__((ext_vector_type(4)));

#define MFMA16(A, B, Cc) __builtin_amdgcn_mfma_f32_16x16x32_bf16(A, B, Cc, 0, 0, 0)

constexpr int NN = 768;   // sequence dim
constexpr int CC = 128;   // channels
constexpr int XP = 152;   // padded LDS stride for LN tiles (bank-friendly, 16B-mult)

__device__ __forceinline__ float bfu_to_f(unsigned short u) {
    return __uint_as_float(((unsigned)u) << 16);
}
__device__ __forceinline__ float sigmoidf_(float x) {
    return 1.f / (1.f + __expf(-x));
}

// ---------------------------------------------------------------------------
// Kernel W: cast fp32 weight matrices to bf16 once into ws.
// layout in wB: proj_w[256x128] | gate_w[256x128] | out_w[128x128] | gating_w[128x128]
// ---------------------------------------------------------------------------
__global__ void kW(const float* __restrict__ proj_w, const float* __restrict__ gate_w,
                   const float* __restrict__ out_w, const float* __restrict__ gating_w,
                   bf16* __restrict__ wB)
{
    int idx = (blockIdx.x * 256 + threadIdx.x) * 4;   // 98304 elems total
    const float* src; int off;
    if (idx < 32768)      { src = proj_w;   off = idx; }
    else if (idx < 65536) { src = gate_w;   off = idx - 32768; }
    else if (idx < 81920) { src = out_w;    off = idx - 65536; }
    else                  { src = gating_w; off = idx - 81920; }
    float4 v = *(const float4*)(src + off);
    bf16 o[4] = {(bf16)v.x, (bf16)v.y, (bf16)v.z, (bf16)v.w};
    *(uint2*)(wB + idx) = *(const uint2*)o;
}

// ---------------------------------------------------------------------------
// Kernel A: LN1 (fp32 in) + [proj|gate] GEMM (32x512xK128, bf16 MFMA) +
// sigmoid/mask/deinterleave. Block = 256 thr, 32 rows r = i*768+k (same i).
// Writes aT,bT in [c][i][k] channel-major layout (64B runs per thread).
// ---------------------------------------------------------------------------
__global__ __launch_bounds__(256, 2) void kA(
    const float* __restrict__ pair, const float* __restrict__ mask,
    const float* __restrict__ ln1_w, const float* __restrict__ ln1_b,
    const bf16* __restrict__ wB,
    bf16* __restrict__ aT, bf16* __restrict__ bT)
{
    __shared__ bf16 xs[32][XP];    // LN1 output
    __shared__ bf16 ob[32][520];   // GEMM out: cols 0..255 proj, 256..511 gate

    const int tid  = threadIdx.x;
    const int lane = tid & 63;
    const int wv   = tid >> 6;
    const int r0   = blockIdx.x * 32;
    const int i    = r0 / NN;
    const int k0   = r0 % NN;

    // ---- LN1: wave wv owns rows wv*8..+7; loads fp32 pair, writes bf16 xs
    {
        float g0 = ln1_w[lane], g1 = ln1_w[lane + 64];
        float b0 = ln1_b[lane], b1 = ln1_b[lane + 64];
        for (int rr = 0; rr < 8; ++rr) {
            int row = wv * 8 + rr;
            const float* pr = pair + (size_t)(r0 + row) * CC;
            float v0 = pr[lane], v1 = pr[lane + 64];
            float s = v0 + v1, q = v0 * v0 + v1 * v1;
            for (int off = 32; off > 0; off >>= 1) {
                s += __shfl_xor(s, off);
                q += __shfl_xor(q, off);
            }
            float mu   = s * (1.f / 128.f);
            float rstd = rsqrtf(q * (1.f / 128.f) - mu * mu + 1e-5f);
            xs[row][lane]      = (bf16)((v0 - mu) * rstd * g0 + b0);
            xs[row][lane + 64] = (bf16)((v1 - mu) * rstd * g1 + b1);
        }
    }
    __syncthreads();

    // ---- GEMM: D(32x512) = X(32x128) @ W512^T ; wave wv owns n = wv*128..+127
    {
        const int m = lane & 15, quad = lane >> 4;
        const bf16* wProj = wB;
        const bf16* wGate = wB + 32768;
        f32x4 acc[2][8] = {};
        for (int ks = 0; ks < 4; ++ks) {
            bf16x8 a0 = *(const bf16x8*)&xs[m][ks * 32 + quad * 8];
            bf16x8 a1 = *(const bf16x8*)&xs[m + 16][ks * 32 + quad * 8];
            for (int t = 0; t < 8; ++t) {
                int n0 = wv * 128 + t * 16;
                const bf16* wp = (n0 < 256) ? (wProj + (size_t)n0 * CC)
                                            : (wGate + (size_t)(n0 - 256) * CC);
                bf16x8 bfr = *(const bf16x8*)(wp + (size_t)m * CC + ks * 32 + quad * 8);
                acc[0][t] = MFMA16(a0, bfr, acc[0][t]);
                acc[1][t] = MFMA16(a1, bfr, acc[1][t]);
            }
        }
        // C layout: col = lane&15 (n), row = quad*4 + reg (m)
        for (int t = 0; t < 8; ++t) {
            int n = wv * 128 + t * 16 + m;
            for (int mt = 0; mt < 2; ++mt)
                for (int r = 0; r < 4; ++r)
                    ob[mt * 16 + quad * 4 + r][n] = (bf16)acc[mt][t][r];
        }
    }
    __syncthreads();

    // ---- a/b epilogue: thread t<128 -> a channel t; t>=128 -> b channel t-128.
    {
        const int isB = tid >> 7;
        const int ch  = tid & 127;
        unsigned packed[16];
        bf16* o = (bf16*)packed;
        for (int mm = 0; mm < 32; ++mm) {
            unsigned pw = *(const unsigned*)&ob[mm][2 * ch];         // proj 2c|2c+1
            unsigned gw = *(const unsigned*)&ob[mm][256 + 2 * ch];   // gate 2c|2c+1
            unsigned short pu = isB ? (unsigned short)(pw >> 16) : (unsigned short)(pw & 0xffffu);
            unsigned short gu = isB ? (unsigned short)(gw >> 16) : (unsigned short)(gw & 0xffffu);
            float p  = bfu_to_f(pu);
            float g  = bfu_to_f(gu);
            float mk = mask[k0 + mm];
            o[mm] = (bf16)(p * mk * sigmoidf_(g));
        }
        bf16* dst = (isB ? bT : aT) + (size_t)ch * NN * NN + (size_t)i * NN + k0;
        for (int qq = 0; qq < 4; ++qq)
            ((uint4*)dst)[qq] = ((const uint4*)packed)[qq];
    }
}

// ---------------------------------------------------------------------------
// Kernel B: per-channel NT-GEMM  oT[c] = A_c(768x768) * B_c(768x768)^T.
// 128x128 tile, BK=32, 4 waves in 2x2, each wave 64x64 (4x4 frags 16x16x32).
// v2: XCD-affinity swizzle (all 36 tiles of a channel on one XCD -> A/B panels
//     stay L2-resident, 6x reuse), register prefetch of next K-step (latency
//     hides under frag reads + MFMA), LDS-staged full-line output stores.
// ---------------------------------------------------------------------------
__global__ __launch_bounds__(256, 2) void kB(
    const bf16* __restrict__ aT, const bf16* __restrict__ bT,
    bf16* __restrict__ oT)
{
    __shared__ __align__(16) bf16 smem[8192];   // As[4096] | Bs[4096]; reused as 64x128 out-stage
    bf16* As = smem;
    bf16* Bs = smem + 4096;

    const int tid  = threadIdx.x;
    const int lane = tid & 63;
    const int wv   = tid >> 6;

    // XCD-affinity swizzle: hardware round-robins blockIdx across the 8 XCDs,
    // so give XCD x the contiguous work range [x*576, (x+1)*576).
    // 576 = 16 channels * 36 tiles -> each channel's A+B (2.25 MB) is L2-resident.
    const int bid = blockIdx.x;
    const int w   = (bid & 7) * ((CC * 36) / 8) + (bid >> 3);
    const int c   = w / 36;
    const int t   = w % 36;
    const int i0  = (t / 6) * 128, j0 = (t % 6) * 128;

    const bf16* Ab = aT + (size_t)c * NN * NN;
    const bf16* Bb = bT + (size_t)c * NN * NN;
    const int wm = wv & 1, wn = wv >> 1;
    const int m = lane & 15, quad = lane >> 4;

    f32x4 acc[4][4] = {};
    uint4 av[2], bv[2];

    // prefetch K-step 0
    for (int h = 0; h < 2; ++h) {
        int chunk = h * 256 + tid;          // 512 x 16B chunks per operand
        int row = chunk >> 2, part = chunk & 3;
        av[h] = *(const uint4*)(Ab + (size_t)(i0 + row) * NN + part * 8);
        bv[h] = *(const uint4*)(Bb + (size_t)(j0 + row) * NN + part * 8);
    }

    for (int ks = 0; ks < 24; ++ks) {
        __syncthreads();   // previous tile's frag reads complete
        for (int h = 0; h < 2; ++h) {
            int chunk = h * 256 + tid;
            int row = chunk >> 2, part = chunk & 3;
            int slot = part ^ ((row >> 1) & 3);
            *(uint4*)&As[row * 32 + slot * 8] = av[h];
            *(uint4*)&Bs[row * 32 + slot * 8] = bv[h];
        }
        __syncthreads();   // tile visible
        if (ks < 23) {     // issue next K-step's loads; latency hides under MFMA
            const int k0 = (ks + 1) * 32;
            for (int h = 0; h < 2; ++h) {
                int chunk = h * 256 + tid;
                int row = chunk >> 2, part = chunk & 3;
                av[h] = *(const uint4*)(Ab + (size_t)(i0 + row) * NN + k0 + part * 8);
                bv[h] = *(const uint4*)(Bb + (size_t)(j0 + row) * NN + k0 + part * 8);
            }
        }
        bf16x8 af[4], bf_[4];
        for (int mt = 0; mt < 4; ++mt) {
            int row = wm * 64 + mt * 16 + m;
            int slot = quad ^ ((row >> 1) & 3);
            af[mt] = *(const bf16x8*)&As[row * 32 + slot * 8];
        }
        for (int nt = 0; nt < 4; ++nt) {
            int row = wn * 64 + nt * 16 + m;
            int slot = quad ^ ((row >> 1) & 3);
            bf_[nt] = *(const bf16x8*)&Bs[row * 32 + slot * 8];
        }
        for (int mt = 0; mt < 4; ++mt)
            for (int nt = 0; nt < 4; ++nt)
                acc[mt][nt] = MFMA16(af[mt], bf_[nt], acc[mt][nt]);
    }

    // ---- epilogue: stage each 64-row half in LDS (XOR-swizzled), then write
    // 64 contiguous bytes per lane -> full 128B-line HBM writes.
    bf16* ob = oT + (size_t)c * NN * NN;
    for (int p = 0; p < 2; ++p) {
        __syncthreads();   // frag reads (p=0) / previous pass's LDS reads (p=1) done
        if (wm == p) {
            for (int mt = 0; mt < 4; ++mt)
                for (int nt = 0; nt < 4; ++nt) {
                    int rb = mt * 16 + quad * 4;                 // local row base 0..63
                    for (int r = 0; r < 4; ++r) {
                        int rr = rb + r;
                        // physical col = col ^ (quad<<4) ^ ((rr&3)<<3); (rr>>2)&3 == quad
                        int colb = (wn * 64 + nt * 16 + m) ^ (quad << 4) ^ ((rr & 3) << 3);
                        smem[rr * 128 + colb] = (bf16)acc[mt][nt][r];
                    }
                }
        }
        __syncthreads();
        const int rr = tid >> 2, q = tid & 3;
        const int swz = (((rr >> 2) & 3) << 4) ^ ((rr & 3) << 3);
        bf16* dst = ob + (size_t)(i0 + p * 64 + rr) * NN + (j0 + q * 32);
        for (int cc = 0; cc < 4; ++cc) {
            int col = (q * 32 + cc * 8) ^ swz;
            ((uint4*)dst)[cc] = *(const uint4*)&smem[rr * 128 + col];
        }
    }
}

// ---------------------------------------------------------------------------
// Kernel C: LN2(oT) @ out_w^T  *  sigmoid(LN1(pair) @ gating_w^T), fp32 out.
// Block = 256 thr, 32 rows r = i*768+j (same i, consecutive j).
// ---------------------------------------------------------------------------
__global__ __launch_bounds__(256, 2) void kC(
    const bf16* __restrict__ oT, const float* __restrict__ pair,
    const float* __restrict__ ln1_w, const float* __restrict__ ln1_b,
    const float* __restrict__ ln2_w, const float* __restrict__ ln2_b,
    const bf16* __restrict__ wB, float* __restrict__ out)
{
    __shared__ bf16 x1[32][XP];   // LN1(pair) rows (i, j0..j0+31)
    __shared__ bf16 x2[32][XP];   // LN2(einsum) rows

    const int tid  = threadIdx.x;
    const int lane = tid & 63;
    const int wv   = tid >> 6;
    const int r0   = blockIdx.x * 32;
    const int i    = r0 / NN;
    const int j0   = r0 % NN;

    // ---- gather 32 j's x 128 c from channel-major oT, transpose into x2 (raw)
    {
        int cch = tid >> 1, jp = (tid & 1) * 16;
        const bf16* src = oT + (size_t)cch * NN * NN + (size_t)i * NN + j0 + jp;
        bf16 v[16];
        *(uint4*)&v[0] = ((const uint4*)src)[0];
        *(uint4*)&v[8] = ((const uint4*)src)[1];
        for (int q = 0; q < 16; ++q) x2[jp + q][cch] = v[q];
    }

    // ---- LN1 on pair rows (fp32 direct loads), write bf16 x1
    {
        float g0 = ln1_w[lane], g1 = ln1_w[lane + 64];
        float b0 = ln1_b[lane], b1 = ln1_b[lane + 64];
        for (int rr = 0; rr < 8; ++rr) {
            int row = wv * 8 + rr;
            const float* pr = pair + (size_t)(r0 + row) * CC;
            float v0 = pr[lane], v1 = pr[lane + 64];
            float s = v0 + v1, q = v0 * v0 + v1 * v1;
            for (int off = 32; off > 0; off >>= 1) {
                s += __shfl_xor(s, off);
                q += __shfl_xor(q, off);
            }
            float mu   = s * (1.f / 128.f);
            float rstd = rsqrtf(q * (1.f / 128.f) - mu * mu + 1e-5f);
            x1[row][lane]      = (bf16)((v0 - mu) * rstd * g0 + b0);
            x1[row][lane + 64] = (bf16)((v1 - mu) * rstd * g1 + b1);
        }
    }
    __syncthreads();

    // ---- LN2 on x2 in place
    {
        float g0 = ln2_w[lane], g1 = ln2_w[lane + 64];
        float b0 = ln2_b[lane], b1 = ln2_b[lane + 64];
        for (int rr = 0; rr < 8; ++rr) {
            int row = wv * 8 + rr;
            float v0 = (float)x2[row][lane], v1 = (float)x2[row][lane + 64];
            float s = v0 + v1, q = v0 * v0 + v1 * v1;
            for (int off = 32; off > 0; off >>= 1) {
                s += __shfl_xor(s, off);
                q += __shfl_xor(q, off);
            }
            float mu   = s * (1.f / 128.f);
            float rstd = rsqrtf(q * (1.f / 128.f) - mu * mu + 1e-5f);
            x2[row][lane]      = (bf16)((v0 - mu) * rstd * g0 + b0);
            x2[row][lane + 64] = (bf16)((v1 - mu) * rstd * g1 + b1);
        }
    }
    __syncthreads();

    // ---- two GEMMs (32x128xK128): Y = x2 @ out_w^T ; G = x1 @ gating_w^T
    const int m = lane & 15, quad = lane >> 4;
    const bf16* wOut  = wB + 65536;
    const bf16* wGat  = wB + 81920;
    f32x4 accy[2][2] = {}, accg[2][2] = {};
    for (int ks = 0; ks < 4; ++ks) {
        bf16x8 a20 = *(const bf16x8*)&x2[m][ks * 32 + quad * 8];
        bf16x8 a21 = *(const bf16x8*)&x2[m + 16][ks * 32 + quad * 8];
        bf16x8 a10 = *(const bf16x8*)&x1[m][ks * 32 + quad * 8];
        bf16x8 a11 = *(const bf16x8*)&x1[m + 16][ks * 32 + quad * 8];
        for (int nt = 0; nt < 2; ++nt) {
            int n0 = wv * 32 + nt * 16;
            bf16x8 bo = *(const bf16x8*)(wOut + (size_t)(n0 + m) * CC + ks * 32 + quad * 8);
            bf16x8 bg = *(const bf16x8*)(wGat + (size_t)(n0 + m) * CC + ks * 32 + quad * 8);
            accy[0][nt] = MFMA16(a20, bo, accy[0][nt]);
            accy[1][nt] = MFMA16(a21, bo, accy[1][nt]);
            accg[0][nt] = MFMA16(a10, bg, accg[0][nt]);
            accg[1][nt] = MFMA16(a11, bg, accg[1][nt]);
        }
    }

    // ---- epilogue: out = Y * sigmoid(G), fp32
    for (int mt = 0; mt < 2; ++mt)
        for (int nt = 0; nt < 2; ++nt) {
            int col = wv * 32 + nt * 16 + m;
            for (int r = 0; r < 4; ++r) {
                size_t off = (size_t)(r0 + mt * 16 + quad * 4 + r) * CC + col;
                out[off] = accy[mt][nt][r] * sigmoidf_(accg[mt][nt][r]);
            }
        }
}

// ---------------------------------------------------------------------------
extern "C" void kernel_launch(void* const* d_in, const int* in_sizes, int n_in,
                              void* d_out, int out_size, void* d_ws, size_t ws_size,
                              hipStream_t stream)
{
    const float* pair     = (const float*)d_in[0];
    const float* mask     = (const float*)d_in[1];
    const float* ln1_w    = (const float*)d_in[2];
    const float* ln1_b    = (const float*)d_in[3];
    const float* proj_w   = (const float*)d_in[4];
    const float* gate_w   = (const float*)d_in[5];
    const float* ln2_w    = (const float*)d_in[6];
    const float* ln2_b    = (const float*)d_in[7];
    const float* out_w    = (const float*)d_in[8];
    const float* gating_w = (const float*)d_in[9];
    float* out = (float*)d_out;

    const size_t plane = (size_t)CC * NN * NN;   // 75,497,472 elems
    bf16* aT = (bf16*)d_ws;          // [c][i][k]
    bf16* bT = aT + plane;           // [c][j][k]
    bf16* oT = bT + plane;           // [c][i][j]
    bf16* wB = oT + plane;           // bf16 weights: proj|gate|out|gating

    kW<<<96, 256, 0, stream>>>(proj_w, gate_w, out_w, gating_w, wB);
    kA<<<(NN * NN) / 32, 256, 0, stream>>>(pair, mask, ln1_w, ln1_b, wB, aT, bT);
    kB<<<CC * 36, 256, 0, stream>>>(aT, bT, oT);
    kC<<<(NN * NN) / 32, 256, 0, stream>>>(oT, pair, ln1_w, ln1_b, ln2_w, ln2_b, wB, out);
}

// Round 3
// 1676.475 us; speedup vs baseline: 1.0725x; 1.0200x over previous
//
#include <hip/hip_runtime.h>
#include <cstdint>
#include <cstddef>

typedef __bf16 bf16;
typedef __bf16 bf16x8 __attribute__((ext_vector_type(8)));
typedef float f32x4 __attribute__((ext_vector_type(4)));

#define MFMA16(A, B, Cc) __builtin_amdgcn_mfma_f32_16x16x32_bf16(A, B, Cc, 0, 0, 0)

constexpr int NN = 768;   // sequence dim
constexpr int CC = 128;   // channels
constexpr int XP = 152;   // padded LDS stride for LN tiles (bank-friendly, 16B-mult)

__device__ __forceinline__ float bfu_to_f(unsigned short u) {
    return __uint_as_float(((unsigned)u) << 16);
}
__device__ __forceinline__ float sigmoidf_(float x) {
    return 1.f / (1.f + __expf(-x));
}

// ---------------------------------------------------------------------------
// Kernel W: cast fp32 weight matrices to bf16 once into ws.
// layout in wB: proj_w[256x128] | gate_w[256x128] | out_w[128x128] | gating_w[128x128]
// ---------------------------------------------------------------------------
__global__ void kW(const float* __restrict__ proj_w, const float* __restrict__ gate_w,
                   const float* __restrict__ out_w, const float* __restrict__ gating_w,
                   bf16* __restrict__ wB)
{
    int idx = (blockIdx.x * 256 + threadIdx.x) * 4;   // 98304 elems total
    const float* src; int off;
    if (idx < 32768)      { src = proj_w;   off = idx; }
    else if (idx < 65536) { src = gate_w;   off = idx - 32768; }
    else if (idx < 81920) { src = out_w;    off = idx - 65536; }
    else                  { src = gating_w; off = idx - 81920; }
    float4 v = *(const float4*)(src + off);
    bf16 o[4] = {(bf16)v.x, (bf16)v.y, (bf16)v.z, (bf16)v.w};
    *(uint2*)(wB + idx) = *(const uint2*)o;
}

// ---------------------------------------------------------------------------
// Kernel A: LN1 (fp32 in) + [proj|gate] GEMM (32x512xK128, bf16 MFMA) +
// sigmoid/mask/deinterleave. Block = 256 thr, 32 rows r = i*768+k (same i).
// v3: epilogue stores full 64-B sectors per instruction (4 lanes = one
// channel's 64-B k-run) instead of per-lane scattered uint4s at 1.18 MB
// stride -> kills partial-sector write amplification on aT/bT.
// ---------------------------------------------------------------------------
__global__ __launch_bounds__(256, 2) void kA(
    const float* __restrict__ pair, const float* __restrict__ mask,
    const float* __restrict__ ln1_w, const float* __restrict__ ln1_b,
    const bf16* __restrict__ wB,
    bf16* __restrict__ aT, bf16* __restrict__ bT)
{
    __shared__ bf16 xs[32][XP];    // LN1 output
    __shared__ bf16 ob[32][522];   // GEMM out: cols 0..255 proj, 256..511 gate (522: bank-spread)

    const int tid  = threadIdx.x;
    const int lane = tid & 63;
    const int wv   = tid >> 6;
    const int r0   = blockIdx.x * 32;
    const int i    = r0 / NN;
    const int k0   = r0 % NN;

    // ---- LN1: wave wv owns rows wv*8..+7; loads fp32 pair, writes bf16 xs
    {
        float g0 = ln1_w[lane], g1 = ln1_w[lane + 64];
        float b0 = ln1_b[lane], b1 = ln1_b[lane + 64];
        for (int rr = 0; rr < 8; ++rr) {
            int row = wv * 8 + rr;
            const float* pr = pair + (size_t)(r0 + row) * CC;
            float v0 = pr[lane], v1 = pr[lane + 64];
            float s = v0 + v1, q = v0 * v0 + v1 * v1;
            for (int off = 32; off > 0; off >>= 1) {
                s += __shfl_xor(s, off);
                q += __shfl_xor(q, off);
            }
            float mu   = s * (1.f / 128.f);
            float rstd = rsqrtf(q * (1.f / 128.f) - mu * mu + 1e-5f);
            xs[row][lane]      = (bf16)((v0 - mu) * rstd * g0 + b0);
            xs[row][lane + 64] = (bf16)((v1 - mu) * rstd * g1 + b1);
        }
    }
    __syncthreads();

    // ---- GEMM: D(32x512) = X(32x128) @ W512^T ; wave wv owns n = wv*128..+127
    {
        const int m = lane & 15, quad = lane >> 4;
        const bf16* wProj = wB;
        const bf16* wGate = wB + 32768;
        f32x4 acc[2][8] = {};
        for (int ks = 0; ks < 4; ++ks) {
            bf16x8 a0 = *(const bf16x8*)&xs[m][ks * 32 + quad * 8];
            bf16x8 a1 = *(const bf16x8*)&xs[m + 16][ks * 32 + quad * 8];
            for (int t = 0; t < 8; ++t) {
                int n0 = wv * 128 + t * 16;
                const bf16* wp = (n0 < 256) ? (wProj + (size_t)n0 * CC)
                                            : (wGate + (size_t)(n0 - 256) * CC);
                bf16x8 bfr = *(const bf16x8*)(wp + (size_t)m * CC + ks * 32 + quad * 8);
                acc[0][t] = MFMA16(a0, bfr, acc[0][t]);
                acc[1][t] = MFMA16(a1, bfr, acc[1][t]);
            }
        }
        // C layout: col = lane&15 (n), row = quad*4 + reg (m)
        for (int t = 0; t < 8; ++t) {
            int n = wv * 128 + t * 16 + m;
            for (int mt = 0; mt < 2; ++mt)
                for (int r = 0; r < 4; ++r)
                    ob[mt * 16 + quad * 4 + r][n] = (bf16)acc[mt][t][r];
        }
    }
    __syncthreads();

    // ---- a/b epilogue v3: 4 rounds of (isB, channel-half). Thread handles
    // channel ch = half*64 + (tid>>2), k-chunk = (tid&3)*8 -> one uint4 store.
    // 4 consecutive lanes = 64 contiguous bytes (full sector) per instruction.
    {
        for (int rr4 = 0; rr4 < 4; ++rr4) {
            const int isB   = rr4 >> 1;
            const int ch    = (rr4 & 1) * 64 + (tid >> 2);
            const int chunk = tid & 3;
            unsigned packed[4];
            bf16* o = (bf16*)packed;
            for (int q = 0; q < 8; ++q) {
                int mm = chunk * 8 + q;
                unsigned pw = *(const unsigned*)&ob[mm][2 * ch];         // proj 2c|2c+1
                unsigned gw = *(const unsigned*)&ob[mm][256 + 2 * ch];   // gate 2c|2c+1
                unsigned short pu = isB ? (unsigned short)(pw >> 16) : (unsigned short)(pw & 0xffffu);
                unsigned short gu = isB ? (unsigned short)(gw >> 16) : (unsigned short)(gw & 0xffffu);
                float p  = bfu_to_f(pu);
                float g  = bfu_to_f(gu);
                o[q] = (bf16)(p * mask[k0 + mm] * sigmoidf_(g));
            }
            bf16* dst = (isB ? bT : aT) + (size_t)ch * NN * NN + (size_t)i * NN + k0 + chunk * 8;
            *(uint4*)dst = *(const uint4*)packed;
        }
    }
}

// ---------------------------------------------------------------------------
// Kernel B: per-channel NT-GEMM  oT[c] = A_c(768x768) * B_c(768x768)^T.
// 128x128 tile, BK=32, 4 waves in 2x2, each wave 64x64 (4x4 frags 16x16x32).
// v3: epilogue drain remapped so 16 consecutive lanes write 256 contiguous
// bytes (full 128-B lines) per store instruction.
// ---------------------------------------------------------------------------
__global__ __launch_bounds__(256, 2) void kB(
    const bf16* __restrict__ aT, const bf16* __restrict__ bT,
    bf16* __restrict__ oT)
{
    __shared__ __align__(16) bf16 smem[8192];   // As[4096] | Bs[4096]; reused as 64x128 out-stage
    bf16* As = smem;
    bf16* Bs = smem + 4096;

    const int tid  = threadIdx.x;
    const int lane = tid & 63;
    const int wv   = tid >> 6;

    // XCD-affinity swizzle: hardware round-robins blockIdx across the 8 XCDs,
    // so give XCD x the contiguous work range [x*576, (x+1)*576).
    // 576 = 16 channels * 36 tiles -> each channel's A+B (2.25 MB) is L2-resident.
    const int bid = blockIdx.x;
    const int w   = (bid & 7) * ((CC * 36) / 8) + (bid >> 3);
    const int c   = w / 36;
    const int t   = w % 36;
    const int i0  = (t / 6) * 128, j0 = (t % 6) * 128;

    const bf16* Ab = aT + (size_t)c * NN * NN;
    const bf16* Bb = bT + (size_t)c * NN * NN;
    const int wm = wv & 1, wn = wv >> 1;
    const int m = lane & 15, quad = lane >> 4;

    f32x4 acc[4][4] = {};
    uint4 av[2], bv[2];

    // prefetch K-step 0
    for (int h = 0; h < 2; ++h) {
        int chunk = h * 256 + tid;          // 512 x 16B chunks per operand
        int row = chunk >> 2, part = chunk & 3;
        av[h] = *(const uint4*)(Ab + (size_t)(i0 + row) * NN + part * 8);
        bv[h] = *(const uint4*)(Bb + (size_t)(j0 + row) * NN + part * 8);
    }

    for (int ks = 0; ks < 24; ++ks) {
        __syncthreads();   // previous tile's frag reads complete
        for (int h = 0; h < 2; ++h) {
            int chunk = h * 256 + tid;
            int row = chunk >> 2, part = chunk & 3;
            int slot = part ^ ((row >> 1) & 3);
            *(uint4*)&As[row * 32 + slot * 8] = av[h];
            *(uint4*)&Bs[row * 32 + slot * 8] = bv[h];
        }
        __syncthreads();   // tile visible
        if (ks < 23) {     // issue next K-step's loads; latency hides under MFMA
            const int k0 = (ks + 1) * 32;
            for (int h = 0; h < 2; ++h) {
                int chunk = h * 256 + tid;
                int row = chunk >> 2, part = chunk & 3;
                av[h] = *(const uint4*)(Ab + (size_t)(i0 + row) * NN + k0 + part * 8);
                bv[h] = *(const uint4*)(Bb + (size_t)(j0 + row) * NN + k0 + part * 8);
            }
        }
        bf16x8 af[4], bf_[4];
        for (int mt = 0; mt < 4; ++mt) {
            int row = wm * 64 + mt * 16 + m;
            int slot = quad ^ ((row >> 1) & 3);
            af[mt] = *(const bf16x8*)&As[row * 32 + slot * 8];
        }
        for (int nt = 0; nt < 4; ++nt) {
            int row = wn * 64 + nt * 16 + m;
            int slot = quad ^ ((row >> 1) & 3);
            bf_[nt] = *(const bf16x8*)&Bs[row * 32 + slot * 8];
        }
        for (int mt = 0; mt < 4; ++mt)
            for (int nt = 0; nt < 4; ++nt)
                acc[mt][nt] = MFMA16(af[mt], bf_[nt], acc[mt][nt]);
    }

    // ---- epilogue: stage each 64-row half in LDS (XOR-swizzled), then drain
    // with 16 lanes covering 256 contiguous bytes of one row per instruction
    // (full 128-B HBM lines, no partial-sector writes).
    bf16* ob = oT + (size_t)c * NN * NN;
    for (int p = 0; p < 2; ++p) {
        __syncthreads();   // frag reads (p=0) / previous pass's LDS reads (p=1) done
        if (wm == p) {
            for (int mt = 0; mt < 4; ++mt)
                for (int nt = 0; nt < 4; ++nt) {
                    int rb = mt * 16 + quad * 4;                 // local row base 0..63
                    for (int r = 0; r < 4; ++r) {
                        int rr = rb + r;
                        // physical col = col ^ (quad<<4) ^ ((rr&3)<<3); (rr>>2)&3 == quad
                        int colb = (wn * 64 + nt * 16 + m) ^ (quad << 4) ^ ((rr & 3) << 3);
                        smem[rr * 128 + colb] = (bf16)acc[mt][nt][r];
                    }
                }
        }
        __syncthreads();
        const int lrow  = tid >> 4;   // 0..15
        const int chunk = tid & 15;   // 16-B chunk within the row's 256-B span
        for (int ss = 0; ss < 4; ++ss) {
            int rr  = ss * 16 + lrow;
            int col = (chunk * 8) ^ (((rr >> 2) & 3) << 4) ^ ((rr & 3) << 3);
            uint4 v = *(const uint4*)&smem[rr * 128 + col];
            *(uint4*)(ob + (size_t)(i0 + p * 64 + rr) * NN + j0 + chunk * 8) = v;
        }
    }
}

// ---------------------------------------------------------------------------
// Kernel C: LN2(oT) @ out_w^T  *  sigmoid(LN1(pair) @ gating_w^T), fp32 out.
// Block = 256 thr, 32 rows r = i*768+j (same i, consecutive j).
// ---------------------------------------------------------------------------
__global__ __launch_bounds__(256, 2) void kC(
    const bf16* __restrict__ oT, const float* __restrict__ pair,
    const float* __restrict__ ln1_w, const float* __restrict__ ln1_b,
    const float* __restrict__ ln2_w, const float* __restrict__ ln2_b,
    const bf16* __restrict__ wB, float* __restrict__ out)
{
    __shared__ bf16 x1[32][XP];   // LN1(pair) rows (i, j0..j0+31)
    __shared__ bf16 x2[32][XP];   // LN2(einsum) rows

    const int tid  = threadIdx.x;
    const int lane = tid & 63;
    const int wv   = tid >> 6;
    const int r0   = blockIdx.x * 32;
    const int i    = r0 / NN;
    const int j0   = r0 % NN;

    // ---- gather 32 j's x 128 c from channel-major oT, transpose into x2 (raw)
    {
        int cch = tid >> 1, jp = (tid & 1) * 16;
        const bf16* src = oT + (size_t)cch * NN * NN + (size_t)i * NN + j0 + jp;
        bf16 v[16];
        *(uint4*)&v[0] = ((const uint4*)src)[0];
        *(uint4*)&v[8] = ((const uint4*)src)[1];
        for (int q = 0; q < 16; ++q) x2[jp + q][cch] = v[q];
    }

    // ---- LN1 on pair rows (fp32 direct loads), write bf16 x1
    {
        float g0 = ln1_w[lane], g1 = ln1_w[lane + 64];
        float b0 = ln1_b[lane], b1 = ln1_b[lane + 64];
        for (int rr = 0; rr < 8; ++rr) {
            int row = wv * 8 + rr;
            const float* pr = pair + (size_t)(r0 + row) * CC;
            float v0 = pr[lane], v1 = pr[lane + 64];
            float s = v0 + v1, q = v0 * v0 + v1 * v1;
            for (int off = 32; off > 0; off >>= 1) {
                s += __shfl_xor(s, off);
                q += __shfl_xor(q, off);
            }
            float mu   = s * (1.f / 128.f);
            float rstd = rsqrtf(q * (1.f / 128.f) - mu * mu + 1e-5f);
            x1[row][lane]      = (bf16)((v0 - mu) * rstd * g0 + b0);
            x1[row][lane + 64] = (bf16)((v1 - mu) * rstd * g1 + b1);
        }
    }
    __syncthreads();

    // ---- LN2 on x2 in place
    {
        float g0 = ln2_w[lane], g1 = ln2_w[lane + 64];
        float b0 = ln2_b[lane], b1 = ln2_b[lane + 64];
        for (int rr = 0; rr < 8; ++rr) {
            int row = wv * 8 + rr;
            float v0 = (float)x2[row][lane], v1 = (float)x2[row][lane + 64];
            float s = v0 + v1, q = v0 * v0 + v1 * v1;
            for (int off = 32; off > 0; off >>= 1) {
                s += __shfl_xor(s, off);
                q += __shfl_xor(q, off);
            }
            float mu   = s * (1.f / 128.f);
            float rstd = rsqrtf(q * (1.f / 128.f) - mu * mu + 1e-5f);
            x2[row][lane]      = (bf16)((v0 - mu) * rstd * g0 + b0);
            x2[row][lane + 64] = (bf16)((v1 - mu) * rstd * g1 + b1);
        }
    }
    __syncthreads();

    // ---- two GEMMs (32x128xK128): Y = x2 @ out_w^T ; G = x1 @ gating_w^T
    const int m = lane & 15, quad = lane >> 4;
    const bf16* wOut  = wB + 65536;
    const bf16* wGat  = wB + 81920;
    f32x4 accy[2][2] = {}, accg[2][2] = {};
    for (int ks = 0; ks < 4; ++ks) {
        bf16x8 a20 = *(const bf16x8*)&x2[m][ks * 32 + quad * 8];
        bf16x8 a21 = *(const bf16x8*)&x2[m + 16][ks * 32 + quad * 8];
        bf16x8 a10 = *(const bf16x8*)&x1[m][ks * 32 + quad * 8];
        bf16x8 a11 = *(const bf16x8*)&x1[m + 16][ks * 32 + quad * 8];
        for (int nt = 0; nt < 2; ++nt) {
            int n0 = wv * 32 + nt * 16;
            bf16x8 bo = *(const bf16x8*)(wOut + (size_t)(n0 + m) * CC + ks * 32 + quad * 8);
            bf16x8 bg = *(const bf16x8*)(wGat + (size_t)(n0 + m) * CC + ks * 32 + quad * 8);
            accy[0][nt] = MFMA16(a20, bo, accy[0][nt]);
            accy[1][nt] = MFMA16(a21, bo, accy[1][nt]);
            accg[0][nt] = MFMA16(a10, bg, accg[0][nt]);
            accg[1][nt] = MFMA16(a11, bg, accg[1][nt]);
        }
    }

    // ---- epilogue: out = Y * sigmoid(G), fp32
    for (int mt = 0; mt < 2; ++mt)
        for (int nt = 0; nt < 2; ++nt) {
            int col = wv * 32 + nt * 16 + m;
            for (int r = 0; r < 4; ++r) {
                size_t off = (size_t)(r0 + mt * 16 + quad * 4 + r) * CC + col;
                out[off] = accy[mt][nt][r] * sigmoidf_(accg[mt][nt][r]);
            }
        }
}

// ---------------------------------------------------------------------------
extern "C" void kernel_launch(void* const* d_in, const int* in_sizes, int n_in,
                              void* d_out, int out_size, void* d_ws, size_t ws_size,
                              hipStream_t stream)
{
    const float* pair     = (const float*)d_in[0];
    const float* mask     = (const float*)d_in[1];
    const float* ln1_w    = (const float*)d_in[2];
    const float* ln1_b    = (const float*)d_in[3];
    const float* proj_w   = (const float*)d_in[4];
    const float* gate_w   = (const float*)d_in[5];
    const float* ln2_w    = (const float*)d_in[6];
    const float* ln2_b    = (const float*)d_in[7];
    const float* out_w    = (const float*)d_in[8];
    const float* gating_w = (const float*)d_in[9];
    float* out = (float*)d_out;

    const size_t plane = (size_t)CC * NN * NN;   // 75,497,472 elems
    bf16* aT = (bf16*)d_ws;          // [c][i][k]
    bf16* bT = aT + plane;           // [c][j][k]
    bf16* oT = bT + plane;           // [c][i][j]
    bf16* wB = oT + plane;           // bf16 weights: proj|gate|out|gating

    kW<<<96, 256, 0, stream>>>(proj_w, gate_w, out_w, gating_w, wB);
    kA<<<(NN * NN) / 32, 256, 0, stream>>>(pair, mask, ln1_w, ln1_b, wB, aT, bT);
    kB<<<CC * 36, 256, 0, stream>>>(aT, bT, oT);
    kC<<<(NN * NN) / 32, 256, 0, stream>>>(oT, pair, ln1_w, ln1_b, ln2_w, ln2_b, wB, out);
}